// Round 5
// baseline (291.723 us; speedup 1.0000x reference)
//
#include <hip/hip_runtime.h>
#include <cstdint>
#include <cstddef>

// Problem constants
#define M_DIM 8192   // batch
#define N_DIM 256    // shared rows (distinct output cols)
#define K_DIM 4096   // in_features
#define OUT_F 4096   // out_features = 16 * N_DIM
// Fused GEMM tiling
#define BM 32        // m-rows per block
#define BN 128       // n-half per block -> grid (256,2) = 512 blocks = 2/CU
#define BK 128       // k per tile (R5: doubled -> 96B global issue/thread/phase)
#define NTH 512      // 8 waves; wave w owns 32m x 16n (Rm=1: zero B redundancy)
#define NKT (K_DIM / BK)  // 32 phases

typedef float    float4_ __attribute__((ext_vector_type(4)));
typedef _Float16 half8   __attribute__((ext_vector_type(8)));

// ---------------------------------------------------------------------------
// Kernel 1: convert shared_weights fp32 -> f16 (2 MB, stays L2/L3-resident)
// ---------------------------------------------------------------------------
__global__ __launch_bounds__(256) void convert_w_kernel(const float* __restrict__ w,
                                                        _Float16* __restrict__ wh) {
  int i = (blockIdx.x * 256 + threadIdx.x) * 8;
  float4_ f0 = *(const float4_*)(w + i);
  float4_ f1 = *(const float4_*)(w + i + 4);
  half8 h;
  h[0] = (_Float16)f0[0]; h[1] = (_Float16)f0[1];
  h[2] = (_Float16)f0[2]; h[3] = (_Float16)f0[3];
  h[4] = (_Float16)f1[0]; h[5] = (_Float16)f1[1];
  h[6] = (_Float16)f1[2]; h[7] = (_Float16)f1[3];
  *(half8*)(wh + i) = h;
}

// ---------------------------------------------------------------------------
// Fused kernel. BK=128: per phase each thread issues 2 float4 (x) + 4 half8
// (B) = 96B; 2-phase x prefetch distance + no-drain barriers keep ~150B/thread
// outstanding so HBM never idles between phases. 32 phases total.
// ---------------------------------------------------------------------------
__device__ __forceinline__ void load_bfrag(half8 b[4], const _Float16* __restrict__ wg,
                                           int kk) {
#pragma unroll
  for (int ks = 0; ks < 4; ++ks)
    b[ks] = *(const half8*)(wg + kk + ks * 32);
}

// A tile [32 rows][128 halves] = 8 KB, 16B granules, swizzle slot = gi^(row&15)
// (extends R4's proven 0-conflict pattern to 16 slots).
__device__ __forceinline__ void stage_a(_Float16* __restrict__ dst,
                                        float4_ x0, float4_ x1) {
  half8 h;
  h[0] = (_Float16)x0[0]; h[1] = (_Float16)x0[1];
  h[2] = (_Float16)x0[2]; h[3] = (_Float16)x0[3];
  h[4] = (_Float16)x1[0]; h[5] = (_Float16)x1[1];
  h[6] = (_Float16)x1[2]; h[7] = (_Float16)x1[3];
  *(half8*)dst = h;  // one ds_write_b128
}

__device__ __forceinline__ void mfma_step(float4_ acc[2], const half8 b[4],
                                          const _Float16* __restrict__ As,
                                          int l16, int quad) {
  __builtin_amdgcn_s_setprio(1);
#pragma unroll
  for (int ks = 0; ks < 4; ++ks) {
    const int gi = ks * 4 + quad;
    const int off0 = ((gi ^ (l16 & 15)) << 3);          // row l16
    const int off1 = ((gi ^ ((16 + l16) & 15)) << 3);   // row 16+l16
    half8 a0 = *(const half8*)(As + l16 * BK + off0);
    half8 a1 = *(const half8*)(As + (16 + l16) * BK + off1);
    acc[0] = __builtin_amdgcn_mfma_f32_16x16x32_f16(a0, b[ks], acc[0], 0, 0, 0);
    acc[1] = __builtin_amdgcn_mfma_f32_16x16x32_f16(a1, b[ks], acc[1], 0, 0, 0);
  }
  __builtin_amdgcn_s_setprio(0);
}

// Publish LDS writes / retire LDS reads, then barrier. No vmcnt drain:
// outstanding global prefetches survive the barrier.
#define PHASE_BARRIER() do {                              \
    __builtin_amdgcn_sched_barrier(0);                    \
    asm volatile("s_waitcnt lgkmcnt(0)" ::: "memory");    \
    __builtin_amdgcn_s_barrier();                         \
    __builtin_amdgcn_sched_barrier(0);                    \
  } while (0)

__global__ __launch_bounds__(NTH, 4) void fused_kernel(const float* __restrict__ x,
                                                       const _Float16* __restrict__ wh,
                                                       const float* __restrict__ bias,
                                                       float* __restrict__ out) {
  __shared__ __align__(16) _Float16 As[2][BM * BK];   // 16384 B, double-buffered
  __shared__ __align__(16) float Ssh[BM][BN + 4];     // 16896 B (pad: 4-bank skew)
  __shared__ __align__(16) float bsh[16 * BN];        //  8192 B  (total 41472)

  const int tid  = threadIdx.x;
  const int wv   = tid >> 6;        // 0..7
  const int lane = tid & 63;
  const int quad = lane >> 4;       // 0..3
  const int l16  = lane & 15;
  const int m0   = blockIdx.x * BM;
  const int nb   = blockIdx.y * BN; // 0 or 128; siblings share x rows via L2

  // ---- bias -> LDS rep-major [16][BN] (published by prologue barrier) ----
  {
    const float4_* b4 = (const float4_*)bias;
    float4_* bs4 = (float4_*)bsh;
    int rep = tid >> 5, c4 = tid & 31;
    bs4[tid] = b4[rep * (N_DIM / 4) + (nb >> 2) + c4];
  }

  // ---- A staging coords: thread t -> row t>>4, granule t&15 (8 f32 -> 16B) ----
  const int arow = tid >> 4;           // 0..31
  const int agi  = tid & 15;           // granule 0..15
  const float* xg = x + (size_t)(m0 + arow) * K_DIM + agi * 8;
  _Float16* awr = &As[0][0] + arow * BK + ((agi ^ (arow & 15)) << 3);

  // ---- B-frag pointer (per-lane, direct from L2-resident wh; Rm=1) ----
  const _Float16* wg = wh + (size_t)(nb + wv * 16 + l16) * K_DIM + quad * 8;

  float4_ acc[2];
  acc[0] = (float4_){0.f, 0.f, 0.f, 0.f};
  acc[1] = (float4_){0.f, 0.f, 0.f, 0.f};

  // ---- prologue: tile0 -> As[0]; x tiles 1,2 in regs (2-phase dist); B0 ----
  half8 bA[4], bB[4];
  float4_ t00 = __builtin_nontemporal_load((const float4_*)(xg));
  float4_ t01 = __builtin_nontemporal_load((const float4_*)(xg + 4));
  float4_ xE0 = __builtin_nontemporal_load((const float4_*)(xg + BK));
  float4_ xE1 = __builtin_nontemporal_load((const float4_*)(xg + BK + 4));
  float4_ xO0 = __builtin_nontemporal_load((const float4_*)(xg + 2 * BK));
  float4_ xO1 = __builtin_nontemporal_load((const float4_*)(xg + 2 * BK + 4));
  load_bfrag(bA, wg, 0);
  stage_a(awr, t00, t01);
  PHASE_BARRIER();  // As[0] + bsh published

  for (int kt = 0; kt < NKT; kt += 2) {
    // even: compute tile kt (As[0], bA); stage kt+1 -> As[1]
    load_bfrag(bB, wg, (kt + 1) * BK);
    stage_a(awr + BM * BK, xE0, xE1);
    {
      const int t3 = (kt + 3 < NKT ? kt + 3 : NKT - 1) * BK;
      xE0 = __builtin_nontemporal_load((const float4_*)(xg + t3));
      xE1 = __builtin_nontemporal_load((const float4_*)(xg + t3 + 4));
    }
    mfma_step(acc, bA, As[0], l16, quad);
    PHASE_BARRIER();  // As[1] ready, As[0] free; vmem stays in flight

    // odd: compute tile kt+1 (As[1], bB); stage kt+2 -> As[0]
    {
      const int tB = (kt + 2 < NKT ? kt + 2 : NKT - 1);
      load_bfrag(bA, wg, tB * BK);
      if (kt + 2 < NKT) stage_a(awr, xO0, xO1);
      const int t4 = (kt + 4 < NKT ? kt + 4 : NKT - 1) * BK;
      xO0 = __builtin_nontemporal_load((const float4_*)(xg + t4));
      xO1 = __builtin_nontemporal_load((const float4_*)(xg + t4 + 4));
    }
    mfma_step(acc, bB, As[1], l16, quad);
    PHASE_BARRIER();  // As[0] ready, As[1] free
  }

  // ---- epilogue 1: S-tile -> LDS (C/D layout: n=l16, m=quad*4+r) ----
#pragma unroll
  for (int mf = 0; mf < 2; ++mf)
#pragma unroll
    for (int r = 0; r < 4; ++r)
      Ssh[mf * 16 + quad * 4 + r][wv * 16 + l16] = acc[mf][r];
  PHASE_BARRIER();

  // ---- epilogue 2: out = S[m][j&255] + bias[j]; 512B-coalesced stores ----
  float4_* out4 = (float4_*)out;
  const float4_* bs4 = (const float4_*)bsh;
#pragma unroll
  for (int p = 0; p < 2; ++p) {
    const int row = wv * 4 + p * 2 + (lane >> 5);  // wave owns 4 m-rows
    const int c4  = lane & 31;                     // float4 col within 128-wide
    float4_ sv = *(const float4_*)(&Ssh[row][c4 * 4]);
    const size_t obase = (size_t)(m0 + row) * (OUT_F / 4) + (nb >> 2);
#pragma unroll
    for (int rep = 0; rep < 16; ++rep)
      __builtin_nontemporal_store(sv + bs4[rep * (BN / 4) + c4],
                                  out4 + obase + rep * (N_DIM / 4) + c4);
  }
}

// ---------------------------------------------------------------------------
extern "C" void kernel_launch(void* const* d_in, const int* in_sizes, int n_in,
                              void* d_out, int out_size, void* d_ws, size_t ws_size,
                              hipStream_t stream) {
  const float* x    = (const float*)d_in[0];
  const float* w    = (const float*)d_in[1];
  const float* bias = (const float*)d_in[2];
  float* out        = (float*)d_out;
  _Float16* wh      = (_Float16*)d_ws;  // 2 MB only

  convert_w_kernel<<<(N_DIM * K_DIM) / (256 * 8), 256, 0, stream>>>(w, wh);
  fused_kernel<<<dim3(M_DIM / BM, 2), NTH, 0, stream>>>(x, wh, bias, out);
}

// Round 6
// 286.966 us; speedup vs baseline: 1.0166x; 1.0166x over previous
//
#include <hip/hip_runtime.h>
#include <cstdint>
#include <cstddef>

// Problem constants
#define M_DIM 8192   // batch
#define N_DIM 256    // shared rows (distinct output cols)
#define K_DIM 4096   // in_features
#define OUT_F 4096   // out_features = 16 * N_DIM
// GEMM tiling (R4 geometry, proven: 0 conflicts, VGPR 44, occ 35%)
#define BM 32        // m-rows per block
#define BN 128       // n-half per block -> grid (256,2) = 512 blocks = 2/CU
#define BK 64        // k per tile
#define NTH 512      // 8 waves; wave w owns 32m x 16n (Rm=1: zero B redundancy)
#define NKT (K_DIM / BK)  // 64

typedef float    float4_ __attribute__((ext_vector_type(4)));
typedef _Float16 half8   __attribute__((ext_vector_type(8)));
typedef _Float16 half4   __attribute__((ext_vector_type(4)));

// ---------------------------------------------------------------------------
// Kernel 1: convert shared_weights fp32 -> f16 (2 MB, stays L2-resident)
// ---------------------------------------------------------------------------
__global__ __launch_bounds__(256) void convert_w_kernel(const float* __restrict__ w,
                                                        _Float16* __restrict__ wh) {
  int i = (blockIdx.x * 256 + threadIdx.x) * 8;
  float4_ f0 = *(const float4_*)(w + i);
  float4_ f1 = *(const float4_*)(w + i + 4);
  half8 h;
  h[0] = (_Float16)f0[0]; h[1] = (_Float16)f0[1];
  h[2] = (_Float16)f0[2]; h[3] = (_Float16)f0[3];
  h[4] = (_Float16)f1[0]; h[5] = (_Float16)f1[1];
  h[6] = (_Float16)f1[2]; h[7] = (_Float16)f1[3];
  *(half8*)(wh + i) = h;
}

// ---------------------------------------------------------------------------
// K1: GEMM loop only (R4 body), stores raw S-partials to P (8 MB) instead of
// the 128 MB expanded out. Near-pure-READ probe of the K-loop: rocprof times
// this dispatch directly -> decomposes the fused kernel's 110 us.
// ---------------------------------------------------------------------------
__device__ __forceinline__ void load_bfrag(half8 b[2], const _Float16* __restrict__ wg,
                                           int kk) {
  b[0] = *(const half8*)(wg + kk);
  b[1] = *(const half8*)(wg + kk + 32);
}

// A tile [32][64] halves, linear, 16B-granule XOR swizzle (granule g of row r
// stored at g ^ (r&7)): bank-uniform writes and b128 reads (measured 0 cf).
__device__ __forceinline__ void stage_a(_Float16* __restrict__ As, int arow, int asw,
                                        float4_ a) {
  half4 h;
  h[0] = (_Float16)a[0]; h[1] = (_Float16)a[1];
  h[2] = (_Float16)a[2]; h[3] = (_Float16)a[3];
  *(half4*)(As + arow * BK + asw) = h;
}

__device__ __forceinline__ void mfma_step(float4_ acc[2], const half8 b[2],
                                          const _Float16* __restrict__ As,
                                          int l16, int quad) {
  __builtin_amdgcn_s_setprio(1);
#pragma unroll
  for (int ks = 0; ks < 2; ++ks) {
    const int off = ((ks * 4 + quad) ^ (l16 & 7)) << 3;  // swizzled k-granule
    half8 a0 = *(const half8*)(As + l16 * BK + off);
    half8 a1 = *(const half8*)(As + (16 + l16) * BK + off);
    acc[0] = __builtin_amdgcn_mfma_f32_16x16x32_f16(a0, b[ks], acc[0], 0, 0, 0);
    acc[1] = __builtin_amdgcn_mfma_f32_16x16x32_f16(a1, b[ks], acc[1], 0, 0, 0);
  }
  __builtin_amdgcn_s_setprio(0);
}

// Publish LDS writes / retire LDS reads, then barrier. No vmcnt drain.
#define PHASE_BARRIER() do {                              \
    __builtin_amdgcn_sched_barrier(0);                    \
    asm volatile("s_waitcnt lgkmcnt(0)" ::: "memory");    \
    __builtin_amdgcn_s_barrier();                         \
    __builtin_amdgcn_sched_barrier(0);                    \
  } while (0)

__global__ __launch_bounds__(NTH, 4) void gemm_p_kernel(const float* __restrict__ x,
                                                        const _Float16* __restrict__ wh,
                                                        float* __restrict__ P) {
  __shared__ __align__(16) _Float16 As[2][BM * BK];   //  8192 B, double-buffered
  __shared__ __align__(16) float Ssh[BM][BN + 4];     // 16896 B (pad: 4-bank skew)

  const int tid  = threadIdx.x;
  const int wv   = tid >> 6;        // 0..7
  const int lane = tid & 63;
  const int quad = lane >> 4;       // 0..3
  const int l16  = lane & 15;
  const int m0   = blockIdx.x * BM;
  const int nb   = blockIdx.y * BN; // 0 or 128

  // ---- A staging coords: 32 rows x 64 f32 per kt; 512 thr x 1 float4 ----
  const int arow = tid >> 4;           // 0..31
  const int ac4  = tid & 15;           // float4 index 0..15
  const int asw  = ((((ac4 >> 1) ^ (arow & 7)) << 3) | ((ac4 & 1) << 2));
  const float* xg = x + (size_t)(m0 + arow) * K_DIM + ac4 * 4;

  // ---- B-frag pointer (per-lane, direct from L2-resident wh; Rm=1) ----
  const _Float16* wg = wh + (size_t)(nb + wv * 16 + l16) * K_DIM + quad * 8;

  float4_ acc[2];
  acc[0] = (float4_){0.f, 0.f, 0.f, 0.f};
  acc[1] = (float4_){0.f, 0.f, 0.f, 0.f};

  // ---- prologue: x 2 k-tiles ahead (nontemporal), B 1 k-tile ahead ----
  half8 bA[2], bB[2];
  float4_ aP0 = __builtin_nontemporal_load((const float4_*)(xg));
  float4_ aP1 = __builtin_nontemporal_load((const float4_*)(xg + BK));
  load_bfrag(bA, wg, 0);
  stage_a(As[0], arow, asw, aP0);
  aP0 = __builtin_nontemporal_load((const float4_*)(xg + 2 * BK));
  PHASE_BARRIER();  // As[0] published

  for (int kt = 0; kt < NKT; kt += 2) {
    // even: compute tile kt (As[0], bA); stage kt+1 -> As[1]
    load_bfrag(bB, wg, (kt + 1) * BK);
    stage_a(As[1], arow, asw, aP1);
    if (kt + 3 < NKT)
      aP1 = __builtin_nontemporal_load((const float4_*)(xg + (kt + 3) * BK));
    mfma_step(acc, bA, As[0], l16, quad);
    PHASE_BARRIER();  // As[1] ready, As[0] free; vmem stays in flight

    // odd: compute tile kt+1 (As[1], bB); stage kt+2 -> As[0]
    if (kt + 2 < NKT) {
      load_bfrag(bA, wg, (kt + 2) * BK);
      stage_a(As[0], arow, asw, aP0);
      if (kt + 4 < NKT)
        aP0 = __builtin_nontemporal_load((const float4_*)(xg + (kt + 4) * BK));
    }
    mfma_step(acc, bB, As[1], l16, quad);
    PHASE_BARRIER();  // As[0] ready, As[1] free
  }

  // ---- epilogue: acc -> Ssh (C/D: n=l16, m=quad*4+r), then P store (8 MB) ----
#pragma unroll
  for (int mf = 0; mf < 2; ++mf)
#pragma unroll
    for (int r = 0; r < 4; ++r)
      Ssh[mf * 16 + quad * 4 + r][wv * 16 + l16] = acc[mf][r];
  PHASE_BARRIER();

  float4_* P4 = (float4_*)P;
#pragma unroll
  for (int p = 0; p < 2; ++p) {
    const int row = wv * 4 + p * 2 + (lane >> 5);  // wave owns 4 m-rows
    const int c4  = lane & 31;                     // float4 col within 128-wide
    float4_ sv = *(const float4_*)(&Ssh[row][c4 * 4]);
    P4[(size_t)(m0 + row) * (N_DIM / 4) + (nb >> 2) + c4] = sv;
  }
}

// ---------------------------------------------------------------------------
// K2: out[m][j] = P[m][j&255] + bias[j]  (pure streaming write probe; R0's
// proven expander at nks=1). 1024 blocks x 256 threads, 8 m-rows/block.
// ---------------------------------------------------------------------------
__global__ __launch_bounds__(256) void expand_kernel(const float* __restrict__ P,
                                                     const float* __restrict__ bias,
                                                     float* __restrict__ out) {
  __shared__ __align__(16) float bsh[OUT_F];
  const int tid = threadIdx.x;
  const float4_* b4 = (const float4_*)bias;
  float4_* bs4 = (float4_*)bsh;
#pragma unroll
  for (int p = 0; p < 4; ++p) bs4[p * 256 + tid] = b4[p * 256 + tid];
  __syncthreads();

  const int ml  = tid >> 6;   // 0..3: m-row within group
  const int c64 = tid & 63;   // float4 index within 256-wide S row
  const float4_* P4 = (const float4_*)P;

#pragma unroll
  for (int pass = 0; pass < 2; ++pass) {
    const int m = blockIdx.x * 8 + pass * 4 + ml;
    float4_ s = P4[(size_t)m * (N_DIM / 4) + c64];
    float4_* orow = (float4_*)(out + (size_t)m * OUT_F);
#pragma unroll
    for (int c = 0; c < 16; ++c)
      __builtin_nontemporal_store(s + bs4[c * 64 + c64], orow + c * 64 + c64);
  }
}

// ---------------------------------------------------------------------------
extern "C" void kernel_launch(void* const* d_in, const int* in_sizes, int n_in,
                              void* d_out, int out_size, void* d_ws, size_t ws_size,
                              hipStream_t stream) {
  const float* x    = (const float*)d_in[0];
  const float* w    = (const float*)d_in[1];
  const float* bias = (const float*)d_in[2];
  float* out        = (float*)d_out;
  _Float16* wh      = (_Float16*)d_ws;                    // 2 MB
  float* P          = (float*)((char*)d_ws + (4u << 20)); // 8 MB partials

  convert_w_kernel<<<(N_DIM * K_DIM) / (256 * 8), 256, 0, stream>>>(w, wh);
  gemm_p_kernel<<<dim3(M_DIM / BM, 2), NTH, 0, stream>>>(x, wh, P);
  expand_kernel<<<M_DIM / 8, 256, 0, stream>>>(P, bias, out);
}